// Round 8
// baseline (20423.166 us; speedup 1.0000x reference)
//
#include <hip/hip_runtime.h>
#include <math.h>

typedef _Float16 f16;
typedef _Float16 f16x8 __attribute__((ext_vector_type(8)));
typedef float f32x4 __attribute__((ext_vector_type(4)));
typedef unsigned long long u64;
typedef unsigned short u16;

#define NWG 160
#define MFMA16 __builtin_amdgcn_mfma_f32_16x16x32_f16

// ---------------- prep kernels ----------------

__global__ __launch_bounds__(256) void prep_copy_x0(const float* __restrict__ x0,
                                                    float* __restrict__ traj,
                                                    f16* __restrict__ xhi,
                                                    f16* __restrict__ xlo,
                                                    unsigned* __restrict__ syncarea) {
    if (blockIdx.x == 0) {
        #pragma unroll
        for (int j = 0; j < 4; ++j) syncarea[threadIdx.x * 4 + j] = 0u;
    }
    int i = blockIdx.x * 256 + threadIdx.x;  // 65536 total
    float v = x0[i];
    traj[i] = v;
    f16 h = (f16)v;
    xhi[i] = h;
    xlo[i] = (f16)(v - (float)h);
}

__global__ __launch_bounds__(256) void prep_cast2(const float* __restrict__ src,
                                                  f16* __restrict__ hi,
                                                  f16* __restrict__ lo) {
    int i = blockIdx.x * 256 + threadIdx.x;
    float v = src[i];
    f16 h = (f16)v;
    hi[i] = h;
    lo[i] = (f16)(v - (float)h);
}

__global__ __launch_bounds__(256) void prep_bias(const float* __restrict__ bih,
                                                 const float* __restrict__ bhh,
                                                 const float* __restrict__ bfc,
                                                 const float* __restrict__ Wih,
                                                 float* __restrict__ b1,
                                                 float* __restrict__ bcmb) {
    int wave = blockIdx.x * 4 + (threadIdx.x >> 6);  // 64 waves total
    int lane = threadIdx.x & 63;
    for (int j = wave * 16; j < wave * 16 + 16; ++j) {
        float s = 0.f;
        for (int o = lane; o < 256; o += 64) s += bfc[o] * Wih[j * 256 + o];
        for (int off = 32; off; off >>= 1) s += __shfl_down(s, off);
        if (lane == 0) {
            float t = bih[j] + bhh[j];
            b1[j] = t;
            bcmb[j] = t + s;
        }
    }
}

__global__ __launch_bounds__(256) void prep_wcmb(const float* __restrict__ Wih,
                                                 const float* __restrict__ Wfc,
                                                 const float* __restrict__ Whh,
                                                 f16* __restrict__ Bt_hi,
                                                 f16* __restrict__ Bt_lo) {
    __shared__ float As[64][65];
    __shared__ float Bs[64][65];
    int j0 = blockIdx.y * 64, k0 = blockIdx.x * 64;
    int tid = threadIdx.x;
    float acc[4][4] = {};
    for (int o0 = 0; o0 < 256; o0 += 64) {
        __syncthreads();
        #pragma unroll
        for (int i = 0; i < 16; ++i) {
            int e = i * 256 + tid;
            int r = e >> 6, c = e & 63;
            As[r][c] = Wih[(j0 + r) * 256 + o0 + c];
            Bs[r][c] = Wfc[(o0 + r) * 1024 + k0 + c];
        }
        __syncthreads();
        int ty = tid >> 4, tx = tid & 15;
        for (int o = 0; o < 64; ++o) {
            float a[4], b[4];
            #pragma unroll
            for (int i = 0; i < 4; ++i) a[i] = As[ty * 4 + i][o];
            #pragma unroll
            for (int i = 0; i < 4; ++i) b[i] = Bs[o][tx * 4 + i];
            #pragma unroll
            for (int i = 0; i < 4; ++i)
                #pragma unroll
                for (int jj = 0; jj < 4; ++jj) acc[i][jj] += a[i] * b[jj];
        }
    }
    int ty = tid >> 4, tx = tid & 15;
    #pragma unroll
    for (int i = 0; i < 4; ++i)
        #pragma unroll
        for (int jj = 0; jj < 4; ++jj) {
            int j = j0 + ty * 4 + i, k = k0 + tx * 4 + jj;
            float v = acc[i][jj] + Whh[j * 1024 + k];
            f16 h = (f16)v;
            Bt_hi[j * 1024 + k] = h;
            Bt_lo[j * 1024 + k] = (f16)(v - (float)h);
        }
}

// ---------------- rollout helpers ----------------

// Coherent (placement-safe) 16B load from the device coherence point.
__device__ __forceinline__ void ld_sc16(f16x8& d, const f16* p) {
    asm volatile("global_load_dwordx4 %0, %1, off sc0 sc1"
                 : "=&v"(d) : "v"(p) : "memory");
}

// Hot spin (no s_sleep) until *p >= tgt. Uniform across the wave.
__device__ __forceinline__ void spin_ge(const unsigned* p, unsigned tgt, bool& gaveup) {
    if (gaveup) return;
    int it = 0;
    while (__hip_atomic_load(p, __ATOMIC_RELAXED, __HIP_MEMORY_SCOPE_AGENT) < tgt) {
        if (++it > (1 << 22)) { gaveup = true; break; }
    }
}

__device__ __forceinline__ void store_h4(f16* ph, f16* pl, size_t off, f32x4 v) {
    u64 whi = 0, wlo = 0;
    #pragma unroll
    for (int j = 0; j < 4; ++j) {
        float t = v[j];
        f16 th = (f16)t;
        f16 tl = (f16)(t - (float)th);
        whi |= (u64)__builtin_bit_cast(u16, th) << (16 * j);
        wlo |= (u64)__builtin_bit_cast(u16, tl) << (16 * j);
    }
    __hip_atomic_store((u64*)(ph + off), whi, __ATOMIC_RELAXED, __HIP_MEMORY_SCOPE_AGENT);
    __hip_atomic_store((u64*)(pl + off), wlo, __ATOMIC_RELAXED, __HIP_MEMORY_SCOPE_AGENT);
}

// ---------------- persistent rollout ----------------
// 16 row-groups x 16 rows. Per group: 8 h-WGs (128 cols each) + 2 y-WGs.
// Wave w of every WG owns k-slice [w*128, w*128+128) == the columns written
// by producer h-WG w of the same group -> per-wave flag polling.

__global__ __launch_bounds__(512, 1) void rollout(
    const f16* __restrict__ x0_hi, const f16* __restrict__ x0_lo,
    const f16* __restrict__ Wih_hi, const f16* __restrict__ Wih_lo,
    const f16* __restrict__ Bt_hi, const f16* __restrict__ Bt_lo,
    const float* __restrict__ b1, const float* __restrict__ bcmb,
    const float* __restrict__ bfc,
    f16* hh0, f16* hl0, f16* hh1, f16* hl1, f16* hh2, f16* hl2,
    float* __restrict__ traj, unsigned* __restrict__ syncarea) {
    __shared__ f16 Ws[64 * 1024];    // 128 KB: W_hi for k<512 (128 cols), swizzled
    __shared__ float Red[16 * 128];  // 8 KB reduction buffer, swizzled

    const int wg = blockIdx.x;
    const int g = wg & 15;    // row group: rows g*16 .. g*16+15
    const int cg = wg >> 4;   // 0..9: 0-7 = h cols cg*128; 8-9 = y cols
    const int tid = threadIdx.x;
    const int lane = tid & 63;
    const int w = tid >> 6;    // wave 0..7 = k-slice owner
    const int l15 = lane & 15;
    const int kq = lane >> 4;  // 0..3
    const bool is_h = (cg < 8);
    const int colbase = is_h ? cg * 128 : 1024 + (cg - 8) * 128;
    const int fr = tid >> 5;         // epilogue row 0..15
    const int fc = (tid & 31) * 4;   // epilogue col base 0..124

    unsigned* flags = syncarea + g * 16;  // slots 0-7: h producers, 8-9: y
    bool gaveup = false;

    // ---- stage W_hi (k < 512) to LDS, XOR-swizzled ----
    {
        const char* gsrc = (const char*)Bt_hi;
        #pragma unroll
        for (int i = 0; i < 16; ++i) {
            int f = (tid + i * 512) * 16;  // byte 0..131072
            int col = f >> 10;             // 0..127
            int kb = f & 1023;             // byte within k<512 row
            f16x8 v = *(const f16x8*)(gsrc + (size_t)(colbase + col) * 2048 + kb);
            *(f16x8*)((char*)Ws + (f ^ ((col & 7) << 4))) = v;
        }
    }
    __syncthreads();

    f32x4 biasv;
    {
        const float* bp = is_h ? (bcmb + colbase + fc) : (bfc + colbase - 1024 + fc);
        biasv = *(const f32x4*)bp;
    }
    const size_t hoff0 = (size_t)(g * 16 + l15) * 1024 + w * 128 + kq * 8;
    const size_t hwoff = (size_t)(g * 16 + fr) * 1024 + colbase + fc;

    // ---- step 1: h_1 = tanh(x0 @ Wih^T + b1) -> buf1 (h-WGs only) ----
    if (is_h) {
        *(f32x4*)&Red[tid * 4] = (f32x4){0.f, 0.f, 0.f, 0.f};
        const int k1 = w * 32 + kq * 8;  // K=256 split 8 ways
        f16x8 xh = *(const f16x8*)(x0_hi + (size_t)(g * 16 + l15) * 256 + k1);
        f16x8 xl = *(const f16x8*)(x0_lo + (size_t)(g * 16 + l15) * 256 + k1);
        f32x4 acc[8] = {};
        #pragma unroll
        for (int nt = 0; nt < 8; ++nt) {
            f16x8 wh = *(const f16x8*)(Wih_hi + (size_t)(colbase + nt * 16 + l15) * 256 + k1);
            f16x8 wl = *(const f16x8*)(Wih_lo + (size_t)(colbase + nt * 16 + l15) * 256 + k1);
            acc[nt] = MFMA16(wh, xh, acc[nt], 0, 0, 0);
            acc[nt] = MFMA16(wh, xl, acc[nt], 0, 0, 0);
            acc[nt] = MFMA16(wl, xh, acc[nt], 0, 0, 0);
        }
        __syncthreads();
        #pragma unroll
        for (int nt = 0; nt < 8; ++nt)
            #pragma unroll
            for (int p = 0; p < 4; ++p) {
                int r = l15, c = nt * 16 + kq * 4 + p;
                atomicAdd(&Red[(r * 128 + c) ^ ((r & 7) << 2)], acc[nt][p]);
            }
        __syncthreads();
        f32x4 v = *(const f32x4*)&Red[(fr * 128 + fc) ^ ((fr & 7) << 2)];
        const float* bp = b1 + colbase + fc;
        f32x4 tv;
        #pragma unroll
        for (int j = 0; j < 4; ++j) tv[j] = tanhf(v[j] + bp[j]);
        store_h4(hh1, hl1, hwoff, tv);
    }
    __syncthreads();  // drain stores
    if (tid == 0 && is_h)
        __hip_atomic_store(&flags[cg], 1u, __ATOMIC_RELAXED, __HIP_MEMORY_SCOPE_AGENT);

    // ---- main loop: step t computes h_t (h-WGs) and y_{t-1} (y-WGs) ----
    f16 *pAh = hh1, *pAl = hl1, *pBh = hh2, *pBl = hl2, *pCh = hh0, *pCl = hl0;
    for (int t = 2; t <= 512; ++t) {
        if (t == 512 && is_h) break;  // y-WGs run one extra step for y_511
        // per-wave: wait for MY producer's slice of h_{t-1}
        spin_ge(&flags[w], (unsigned)(t - 1), gaveup);
        // issue h-slice loads (coherence point)
        f16x8 hf0, hf1, hf2, hf3, lf0, lf1, lf2, lf3;
        ld_sc16(hf0, pAh + hoff0);       ld_sc16(lf0, pAl + hoff0);
        ld_sc16(hf1, pAh + hoff0 + 32);  ld_sc16(lf1, pAl + hoff0 + 32);
        ld_sc16(hf2, pAh + hoff0 + 64);  ld_sc16(lf2, pAl + hoff0 + 64);
        ld_sc16(hf3, pAh + hoff0 + 96);  ld_sc16(lf3, pAl + hoff0 + 96);
        const f16x8 hf[4] = {hf0, hf1, hf2, hf3};
        const f16x8 lf[4] = {lf0, lf1, lf2, lf3};
        *(f32x4*)&Red[tid * 4] = (f32x4){0.f, 0.f, 0.f, 0.f};
        f32x4 acc[8] = {};
        const int swz = (l15 & 7) << 4;
        #pragma unroll
        for (int nt = 0; nt < 8; ++nt) {
            f16x8 wh[4], wl[4];
            #pragma unroll
            for (int kk = 0; kk < 4; ++kk) {
                int k = w * 128 + kq * 8 + kk * 32;
                if (w < 4) {
                    int byte = ((nt * 16 + l15) * 1024 + k * 2) ^ swz;
                    wh[kk] = *(const f16x8*)((const char*)Ws + byte);
                } else {
                    wh[kk] = *(const f16x8*)(Bt_hi + (size_t)(colbase + nt * 16 + l15) * 1024 + k);
                }
                wl[kk] = *(const f16x8*)(Bt_lo + (size_t)(colbase + nt * 16 + l15) * 1024 + k);
            }
            if (nt == 0) {
                asm volatile("s_waitcnt vmcnt(0)" ::: "memory");
                __builtin_amdgcn_sched_barrier(0);
            }
            #pragma unroll
            for (int kk = 0; kk < 4; ++kk) {
                acc[nt] = MFMA16(wh[kk], hf[kk], acc[nt], 0, 0, 0);
                acc[nt] = MFMA16(wh[kk], lf[kk], acc[nt], 0, 0, 0);
                acc[nt] = MFMA16(wl[kk], hf[kk], acc[nt], 0, 0, 0);
            }
        }
        __syncthreads();
        #pragma unroll
        for (int nt = 0; nt < 8; ++nt)
            #pragma unroll
            for (int p = 0; p < 4; ++p) {
                int r = l15, c = nt * 16 + kq * 4 + p;
                atomicAdd(&Red[(r * 128 + c) ^ ((r & 7) << 2)], acc[nt][p]);
            }
        // 3-buffer safety: h producers make sure y-WGs are within 2 steps
        if (tid == 0 && is_h && t >= 4) {
            spin_ge(&flags[8], (unsigned)(t - 2), gaveup);
            spin_ge(&flags[9], (unsigned)(t - 2), gaveup);
        }
        __syncthreads();
        f32x4 v = *(const f32x4*)&Red[(fr * 128 + fc) ^ ((fr & 7) << 2)];
        v += biasv;
        if (is_h) {
            f32x4 tv;
            #pragma unroll
            for (int j = 0; j < 4; ++j) tv[j] = tanhf(v[j]);
            store_h4(pBh, pBl, hwoff, tv);
        } else {
            *(f32x4*)(traj + (size_t)(t - 1) * 65536 + (size_t)(g * 16 + fr) * 256 +
                      (colbase - 1024) + fc) = v;
        }
        __syncthreads();  // drain stores before publishing
        if (tid == 0)
            __hip_atomic_store(&flags[cg], (unsigned)t, __ATOMIC_RELAXED,
                               __HIP_MEMORY_SCOPE_AGENT);
        // rotate: next read = just-written; next write = spare
        f16 *th_ = pAh, *tl_ = pAl;
        pAh = pBh; pAl = pBl;
        pBh = pCh; pBl = pCl;
        pCh = th_; pCl = tl_;
    }
}

// ---------------- launch ----------------

extern "C" void kernel_launch(void* const* d_in, const int* in_sizes, int n_in,
                              void* d_out, int out_size, void* d_ws, size_t ws_size,
                              hipStream_t stream) {
    const float* x0 = (const float*)d_in[0];
    const float* Wih = (const float*)d_in[1];
    const float* bih = (const float*)d_in[2];
    const float* Whh = (const float*)d_in[3];
    const float* bhh = (const float*)d_in[4];
    const float* Wfc = (const float*)d_in[5];
    const float* bfc = (const float*)d_in[6];
    float* traj = (float*)d_out;  // [512][256][256]

    char* w = (char*)d_ws;
    size_t off = 0;
    f16* Bt_hi = (f16*)(w + off); off += 1280u * 1024 * 2;
    f16* Bt_lo = (f16*)(w + off); off += 1280u * 1024 * 2;
    f16* Wih_hi = (f16*)(w + off); off += 1024u * 256 * 2;
    f16* Wih_lo = (f16*)(w + off); off += 1024u * 256 * 2;
    f16* x0_hi = (f16*)(w + off); off += 256u * 256 * 2;
    f16* x0_lo = (f16*)(w + off); off += 256u * 256 * 2;
    f16* hh0 = (f16*)(w + off); off += 256u * 1024 * 2;
    f16* hl0 = (f16*)(w + off); off += 256u * 1024 * 2;
    f16* hh1 = (f16*)(w + off); off += 256u * 1024 * 2;
    f16* hl1 = (f16*)(w + off); off += 256u * 1024 * 2;
    f16* hh2 = (f16*)(w + off); off += 256u * 1024 * 2;
    f16* hl2 = (f16*)(w + off); off += 256u * 1024 * 2;
    float* b1 = (float*)(w + off); off += 4096;
    float* bcmb = (float*)(w + off); off += 4096;
    unsigned* syncarea = (unsigned*)(w + off); off += 4096;

    prep_copy_x0<<<dim3(256), dim3(256), 0, stream>>>(x0, traj, x0_hi, x0_lo, syncarea);
    prep_cast2<<<dim3(1024), dim3(256), 0, stream>>>(Wih, Wih_hi, Wih_lo);
    prep_bias<<<dim3(16), dim3(256), 0, stream>>>(bih, bhh, bfc, Wih, b1, bcmb);
    prep_cast2<<<dim3(1024), dim3(256), 0, stream>>>(Wfc, Bt_hi + 1024 * 1024,
                                                     Bt_lo + 1024 * 1024);
    prep_wcmb<<<dim3(16, 16), dim3(256), 0, stream>>>(Wih, Wfc, Whh, Bt_hi, Bt_lo);

    // persistent rollout: 160 WGs x 512 threads, 1 WG/CU (136 KB LDS).
    // Per-wave producer-matched flag sync; hot spin; coherence-point h traffic
    // -> placement-independent, no cache maintenance, no RMW counters.
    rollout<<<dim3(NWG), dim3(512), 0, stream>>>(
        x0_hi, x0_lo, Wih_hi, Wih_lo, Bt_hi, Bt_lo, b1, bcmb, bfc,
        hh0, hl0, hh1, hl1, hh2, hl2, traj, syncarea);
}

// Round 9
// 20086.072 us; speedup vs baseline: 1.0168x; 1.0168x over previous
//
#include <hip/hip_runtime.h>
#include <math.h>

typedef _Float16 f16;
typedef _Float16 f16x8 __attribute__((ext_vector_type(8)));
typedef float f32x4 __attribute__((ext_vector_type(4)));
typedef unsigned long long u64;
typedef unsigned short u16;

#define NWG 160
#define MFMA16 __builtin_amdgcn_mfma_f32_16x16x32_f16

// ---------------- prep kernels ----------------

__global__ __launch_bounds__(256) void prep_copy_x0(const float* __restrict__ x0,
                                                    float* __restrict__ traj,
                                                    f16* __restrict__ xhi,
                                                    f16* __restrict__ xlo,
                                                    unsigned* __restrict__ syncarea) {
    if (blockIdx.x == 0) {
        #pragma unroll
        for (int j = 0; j < 32; ++j) syncarea[threadIdx.x * 32 + j] = 0u;  // 32 KB
    }
    int i = blockIdx.x * 256 + threadIdx.x;  // 65536 total
    float v = x0[i];
    traj[i] = v;
    f16 h = (f16)v;
    xhi[i] = h;
    xlo[i] = (f16)(v - (float)h);
}

__global__ __launch_bounds__(256) void prep_cast2(const float* __restrict__ src,
                                                  f16* __restrict__ hi,
                                                  f16* __restrict__ lo) {
    int i = blockIdx.x * 256 + threadIdx.x;
    float v = src[i];
    f16 h = (f16)v;
    hi[i] = h;
    lo[i] = (f16)(v - (float)h);
}

__global__ __launch_bounds__(256) void prep_bias(const float* __restrict__ bih,
                                                 const float* __restrict__ bhh,
                                                 const float* __restrict__ bfc,
                                                 const float* __restrict__ Wih,
                                                 float* __restrict__ b1,
                                                 float* __restrict__ bcmb) {
    int wave = blockIdx.x * 4 + (threadIdx.x >> 6);  // 64 waves total
    int lane = threadIdx.x & 63;
    for (int j = wave * 16; j < wave * 16 + 16; ++j) {
        float s = 0.f;
        for (int o = lane; o < 256; o += 64) s += bfc[o] * Wih[j * 256 + o];
        for (int off = 32; off; off >>= 1) s += __shfl_down(s, off);
        if (lane == 0) {
            float t = bih[j] + bhh[j];
            b1[j] = t;
            bcmb[j] = t + s;
        }
    }
}

__global__ __launch_bounds__(256) void prep_wcmb(const float* __restrict__ Wih,
                                                 const float* __restrict__ Wfc,
                                                 const float* __restrict__ Whh,
                                                 f16* __restrict__ Bt_hi,
                                                 f16* __restrict__ Bt_lo) {
    __shared__ float As[64][65];
    __shared__ float Bs[64][65];
    int j0 = blockIdx.y * 64, k0 = blockIdx.x * 64;
    int tid = threadIdx.x;
    float acc[4][4] = {};
    for (int o0 = 0; o0 < 256; o0 += 64) {
        __syncthreads();
        #pragma unroll
        for (int i = 0; i < 16; ++i) {
            int e = i * 256 + tid;
            int r = e >> 6, c = e & 63;
            As[r][c] = Wih[(j0 + r) * 256 + o0 + c];
            Bs[r][c] = Wfc[(o0 + r) * 1024 + k0 + c];
        }
        __syncthreads();
        int ty = tid >> 4, tx = tid & 15;
        for (int o = 0; o < 64; ++o) {
            float a[4], b[4];
            #pragma unroll
            for (int i = 0; i < 4; ++i) a[i] = As[ty * 4 + i][o];
            #pragma unroll
            for (int i = 0; i < 4; ++i) b[i] = Bs[o][tx * 4 + i];
            #pragma unroll
            for (int i = 0; i < 4; ++i)
                #pragma unroll
                for (int jj = 0; jj < 4; ++jj) acc[i][jj] += a[i] * b[jj];
        }
    }
    int ty = tid >> 4, tx = tid & 15;
    #pragma unroll
    for (int i = 0; i < 4; ++i)
        #pragma unroll
        for (int jj = 0; jj < 4; ++jj) {
            int j = j0 + ty * 4 + i, k = k0 + tx * 4 + jj;
            float v = acc[i][jj] + Whh[j * 1024 + k];
            f16 h = (f16)v;
            Bt_hi[j * 1024 + k] = h;
            Bt_lo[j * 1024 + k] = (f16)(v - (float)h);
        }
}

// ---------------- rollout helpers ----------------

// Coherent (placement-safe) 16B load from the device coherence point.
__device__ __forceinline__ void ld_sc16(f16x8& d, const f16* p) {
    asm volatile("global_load_dwordx4 %0, %1, off sc0 sc1"
                 : "=&v"(d) : "v"(p) : "memory");
}

// Spin with VALU-busy backoff: between polls run a dependent FMA chain
// (~0.4us). Keeps the CU issuing (DVFS boost) and backs off the flag line.
__device__ __forceinline__ void spin_ge(const unsigned* p, unsigned tgt, bool& gaveup) {
    if (gaveup) return;
    int it = 0;
    float x = 1.0f;
    while (__hip_atomic_load(p, __ATOMIC_RELAXED, __HIP_MEMORY_SCOPE_AGENT) < tgt) {
        #pragma unroll 8
        for (int j = 0; j < 256; ++j) x = __builtin_fmaf(x, 1.000001f, 1.0f);
        asm volatile("" :: "v"(x));
        if (++it > (1 << 15)) { gaveup = true; break; }
    }
}

__device__ __forceinline__ void store_h4(f16* ph, f16* pl, size_t off, f32x4 v) {
    u64 whi = 0, wlo = 0;
    #pragma unroll
    for (int j = 0; j < 4; ++j) {
        float t = v[j];
        f16 th = (f16)t;
        f16 tl = (f16)(t - (float)th);
        whi |= (u64)__builtin_bit_cast(u16, th) << (16 * j);
        wlo |= (u64)__builtin_bit_cast(u16, tl) << (16 * j);
    }
    __hip_atomic_store((u64*)(ph + off), whi, __ATOMIC_RELAXED, __HIP_MEMORY_SCOPE_AGENT);
    __hip_atomic_store((u64*)(pl + off), wlo, __ATOMIC_RELAXED, __HIP_MEMORY_SCOPE_AGENT);
}

// ---------------- persistent rollout ----------------
// 16 row-groups x 16 rows. Per group: 8 h-WGs (128 cols each) + 2 y-WGs.
// Wave w of every WG owns k-slice [w*128, w*128+128) == the columns written
// by producer h-WG w of the same group -> per-wave flag polling.
// Flags padded to 128 B each (no shared-line contention with producers).

#define FLAG(g, s) (syncarea + ((g) * 10 + (s)) * 32)

__global__ __launch_bounds__(512, 1) void rollout(
    const f16* __restrict__ x0_hi, const f16* __restrict__ x0_lo,
    const f16* __restrict__ Wih_hi, const f16* __restrict__ Wih_lo,
    const f16* __restrict__ Bt_hi, const f16* __restrict__ Bt_lo,
    const float* __restrict__ b1, const float* __restrict__ bcmb,
    const float* __restrict__ bfc,
    f16* hh0, f16* hl0, f16* hh1, f16* hl1, f16* hh2, f16* hl2,
    float* __restrict__ traj, unsigned* __restrict__ syncarea) {
    __shared__ f16 Ws[64 * 1024];    // 128 KB: W_hi for k<512 (128 cols), swizzled
    __shared__ float Red[16 * 128];  // 8 KB reduction buffer, swizzled

    const int wg = blockIdx.x;
    const int g = wg & 15;    // row group: rows g*16 .. g*16+15
    const int cg = wg >> 4;   // 0..9: 0-7 = h cols cg*128; 8-9 = y cols
    const int tid = threadIdx.x;
    const int lane = tid & 63;
    const int w = tid >> 6;    // wave 0..7 = k-slice owner
    const int l15 = lane & 15;
    const int kq = lane >> 4;  // 0..3
    const bool is_h = (cg < 8);
    const int colbase = is_h ? cg * 128 : 1024 + (cg - 8) * 128;
    const int fr = tid >> 5;         // epilogue row 0..15
    const int fc = (tid & 31) * 4;   // epilogue col base 0..124

    bool gaveup = false;

    // ---- stage W_hi (k < 512) to LDS, XOR-swizzled ----
    {
        const char* gsrc = (const char*)Bt_hi;
        #pragma unroll
        for (int i = 0; i < 16; ++i) {
            int f = (tid + i * 512) * 16;  // byte 0..131072
            int col = f >> 10;             // 0..127
            int kb = f & 1023;             // byte within k<512 row
            f16x8 v = *(const f16x8*)(gsrc + (size_t)(colbase + col) * 2048 + kb);
            *(f16x8*)((char*)Ws + (f ^ ((col & 7) << 4))) = v;
        }
    }
    __syncthreads();

    f32x4 biasv;
    {
        const float* bp = is_h ? (bcmb + colbase + fc) : (bfc + colbase - 1024 + fc);
        biasv = *(const f32x4*)bp;
    }
    const size_t hoff0 = (size_t)(g * 16 + l15) * 1024 + w * 128 + kq * 8;
    const size_t hwoff = (size_t)(g * 16 + fr) * 1024 + colbase + fc;

    // ---- step 1: h_1 = tanh(x0 @ Wih^T + b1) -> buf1 (h-WGs only) ----
    if (is_h) {
        *(f32x4*)&Red[tid * 4] = (f32x4){0.f, 0.f, 0.f, 0.f};
        const int k1 = w * 32 + kq * 8;  // K=256 split 8 ways
        f16x8 xh = *(const f16x8*)(x0_hi + (size_t)(g * 16 + l15) * 256 + k1);
        f16x8 xl = *(const f16x8*)(x0_lo + (size_t)(g * 16 + l15) * 256 + k1);
        f32x4 acc[8] = {};
        #pragma unroll
        for (int nt = 0; nt < 8; ++nt) {
            f16x8 wh = *(const f16x8*)(Wih_hi + (size_t)(colbase + nt * 16 + l15) * 256 + k1);
            f16x8 wl = *(const f16x8*)(Wih_lo + (size_t)(colbase + nt * 16 + l15) * 256 + k1);
            acc[nt] = MFMA16(wh, xh, acc[nt], 0, 0, 0);
            acc[nt] = MFMA16(wh, xl, acc[nt], 0, 0, 0);
            acc[nt] = MFMA16(wl, xh, acc[nt], 0, 0, 0);
        }
        __syncthreads();
        #pragma unroll
        for (int nt = 0; nt < 8; ++nt)
            #pragma unroll
            for (int p = 0; p < 4; ++p) {
                int r = l15, c = nt * 16 + kq * 4 + p;
                atomicAdd(&Red[(r * 128 + c) ^ ((r & 7) << 2)], acc[nt][p]);
            }
        __syncthreads();
        f32x4 v = *(const f32x4*)&Red[(fr * 128 + fc) ^ ((fr & 7) << 2)];
        const float* bp = b1 + colbase + fc;
        f32x4 tv;
        #pragma unroll
        for (int j = 0; j < 4; ++j) tv[j] = tanhf(v[j] + bp[j]);
        store_h4(hh1, hl1, hwoff, tv);
    }
    __syncthreads();  // drain stores
    if (tid == 0 && is_h)
        __hip_atomic_store(FLAG(g, cg), 1u, __ATOMIC_RELAXED, __HIP_MEMORY_SCOPE_AGENT);

    // ---- main loop: step t computes h_t (h-WGs) and y_{t-1} (y-WGs) ----
    f16 *pAh = hh1, *pAl = hl1, *pBh = hh2, *pBl = hl2, *pCh = hh0, *pCl = hl0;
    for (int t = 2; t <= 512; ++t) {
        if (t == 512 && is_h) break;  // y-WGs run one extra step for y_511
        // per-wave: wait for MY producer's slice of h_{t-1}
        spin_ge(FLAG(g, w), (unsigned)(t - 1), gaveup);
        // issue h-slice loads (coherence point)
        f16x8 hf0, hf1, hf2, hf3, lf0, lf1, lf2, lf3;
        ld_sc16(hf0, pAh + hoff0);       ld_sc16(lf0, pAl + hoff0);
        ld_sc16(hf1, pAh + hoff0 + 32);  ld_sc16(lf1, pAl + hoff0 + 32);
        ld_sc16(hf2, pAh + hoff0 + 64);  ld_sc16(lf2, pAl + hoff0 + 64);
        ld_sc16(hf3, pAh + hoff0 + 96);  ld_sc16(lf3, pAl + hoff0 + 96);
        const f16x8 hf[4] = {hf0, hf1, hf2, hf3};
        const f16x8 lf[4] = {lf0, lf1, lf2, lf3};
        *(f32x4*)&Red[tid * 4] = (f32x4){0.f, 0.f, 0.f, 0.f};
        f32x4 acc[8] = {};
        const int swz = (l15 & 7) << 4;
        #pragma unroll
        for (int nt = 0; nt < 8; ++nt) {
            f16x8 wh[4], wl[4];
            #pragma unroll
            for (int kk = 0; kk < 4; ++kk) {
                int k = w * 128 + kq * 8 + kk * 32;
                if (w < 4) {
                    int byte = ((nt * 16 + l15) * 1024 + k * 2) ^ swz;
                    wh[kk] = *(const f16x8*)((const char*)Ws + byte);
                } else {
                    wh[kk] = *(const f16x8*)(Bt_hi + (size_t)(colbase + nt * 16 + l15) * 1024 + k);
                }
                wl[kk] = *(const f16x8*)(Bt_lo + (size_t)(colbase + nt * 16 + l15) * 1024 + k);
            }
            if (nt == 0) {
                asm volatile("s_waitcnt vmcnt(0)" ::: "memory");
                __builtin_amdgcn_sched_barrier(0);
            }
            #pragma unroll
            for (int kk = 0; kk < 4; ++kk) {
                acc[nt] = MFMA16(wh[kk], hf[kk], acc[nt], 0, 0, 0);
                acc[nt] = MFMA16(wh[kk], lf[kk], acc[nt], 0, 0, 0);
                acc[nt] = MFMA16(wl[kk], hf[kk], acc[nt], 0, 0, 0);
            }
        }
        __syncthreads();
        #pragma unroll
        for (int nt = 0; nt < 8; ++nt)
            #pragma unroll
            for (int p = 0; p < 4; ++p) {
                int r = l15, c = nt * 16 + kq * 4 + p;
                atomicAdd(&Red[(r * 128 + c) ^ ((r & 7) << 2)], acc[nt][p]);
            }
        // 3-buffer safety: h producers make sure y-WGs are within 2 steps
        if (tid == 0 && is_h && t >= 4) {
            spin_ge(FLAG(g, 8), (unsigned)(t - 2), gaveup);
            spin_ge(FLAG(g, 9), (unsigned)(t - 2), gaveup);
        }
        __syncthreads();
        f32x4 v = *(const f32x4*)&Red[(fr * 128 + fc) ^ ((fr & 7) << 2)];
        v += biasv;
        if (is_h) {
            f32x4 tv;
            #pragma unroll
            for (int j = 0; j < 4; ++j) tv[j] = tanhf(v[j]);
            store_h4(pBh, pBl, hwoff, tv);
        } else {
            *(f32x4*)(traj + (size_t)(t - 1) * 65536 + (size_t)(g * 16 + fr) * 256 +
                      (colbase - 1024) + fc) = v;
        }
        __syncthreads();  // drain stores before publishing
        if (tid == 0)
            __hip_atomic_store(FLAG(g, cg), (unsigned)t, __ATOMIC_RELAXED,
                               __HIP_MEMORY_SCOPE_AGENT);
        // rotate: next read = just-written; next write = spare
        f16 *th_ = pAh, *tl_ = pAl;
        pAh = pBh; pAl = pBl;
        pBh = pCh; pBl = pCl;
        pCh = th_; pCl = tl_;
    }
}

// ---------------- launch ----------------

extern "C" void kernel_launch(void* const* d_in, const int* in_sizes, int n_in,
                              void* d_out, int out_size, void* d_ws, size_t ws_size,
                              hipStream_t stream) {
    const float* x0 = (const float*)d_in[0];
    const float* Wih = (const float*)d_in[1];
    const float* bih = (const float*)d_in[2];
    const float* Whh = (const float*)d_in[3];
    const float* bhh = (const float*)d_in[4];
    const float* Wfc = (const float*)d_in[5];
    const float* bfc = (const float*)d_in[6];
    float* traj = (float*)d_out;  // [512][256][256]

    char* w = (char*)d_ws;
    size_t off = 0;
    f16* Bt_hi = (f16*)(w + off); off += 1280u * 1024 * 2;
    f16* Bt_lo = (f16*)(w + off); off += 1280u * 1024 * 2;
    f16* Wih_hi = (f16*)(w + off); off += 1024u * 256 * 2;
    f16* Wih_lo = (f16*)(w + off); off += 1024u * 256 * 2;
    f16* x0_hi = (f16*)(w + off); off += 256u * 256 * 2;
    f16* x0_lo = (f16*)(w + off); off += 256u * 256 * 2;
    f16* hh0 = (f16*)(w + off); off += 256u * 1024 * 2;
    f16* hl0 = (f16*)(w + off); off += 256u * 1024 * 2;
    f16* hh1 = (f16*)(w + off); off += 256u * 1024 * 2;
    f16* hl1 = (f16*)(w + off); off += 256u * 1024 * 2;
    f16* hh2 = (f16*)(w + off); off += 256u * 1024 * 2;
    f16* hl2 = (f16*)(w + off); off += 256u * 1024 * 2;
    float* b1 = (float*)(w + off); off += 4096;
    float* bcmb = (float*)(w + off); off += 4096;
    unsigned* syncarea = (unsigned*)(w + off); off += 32768;  // padded flags

    prep_copy_x0<<<dim3(256), dim3(256), 0, stream>>>(x0, traj, x0_hi, x0_lo, syncarea);
    prep_cast2<<<dim3(1024), dim3(256), 0, stream>>>(Wih, Wih_hi, Wih_lo);
    prep_bias<<<dim3(16), dim3(256), 0, stream>>>(bih, bhh, bfc, Wih, b1, bcmb);
    prep_cast2<<<dim3(1024), dim3(256), 0, stream>>>(Wfc, Bt_hi + 1024 * 1024,
                                                     Bt_lo + 1024 * 1024);
    prep_wcmb<<<dim3(16, 16), dim3(256), 0, stream>>>(Wih, Wfc, Whh, Bt_hi, Bt_lo);

    // persistent rollout: 160 WGs x 512 threads, 1 WG/CU (136 KB LDS).
    // Per-wave producer-matched flag sync (128B-padded flags); VALU-busy
    // backoff spin (keeps SCLK boosted, backs off flag lines);
    // coherence-point h traffic -> placement-independent.
    rollout<<<dim3(NWG), dim3(512), 0, stream>>>(
        x0_hi, x0_lo, Wih_hi, Wih_lo, Bt_hi, Bt_lo, b1, bcmb, bfc,
        hh0, hl0, hh1, hl1, hh2, hl2, traj, syncarea);
}

// Round 10
// 19893.867 us; speedup vs baseline: 1.0266x; 1.0097x over previous
//
#include <hip/hip_runtime.h>
#include <math.h>

typedef _Float16 f16;
typedef _Float16 f16x8 __attribute__((ext_vector_type(8)));
typedef float f32x4 __attribute__((ext_vector_type(4)));
typedef unsigned long long u64;
typedef unsigned short u16;

#define NWG 160
#define MFMA16 __builtin_amdgcn_mfma_f32_16x16x32_f16

// ---------------- prep kernels ----------------

__global__ __launch_bounds__(256) void prep_copy_x0(const float* __restrict__ x0,
                                                    float* __restrict__ traj,
                                                    f16* __restrict__ xhi,
                                                    f16* __restrict__ xlo,
                                                    unsigned* __restrict__ syncarea) {
    if (blockIdx.x == 0) {
        #pragma unroll
        for (int j = 0; j < 32; ++j) syncarea[threadIdx.x * 32 + j] = 0u;  // 32 KB
    }
    int i = blockIdx.x * 256 + threadIdx.x;  // 65536 total
    float v = x0[i];
    traj[i] = v;
    f16 h = (f16)v;
    xhi[i] = h;
    xlo[i] = (f16)(v - (float)h);
}

__global__ __launch_bounds__(256) void prep_cast2(const float* __restrict__ src,
                                                  f16* __restrict__ hi,
                                                  f16* __restrict__ lo) {
    int i = blockIdx.x * 256 + threadIdx.x;
    float v = src[i];
    f16 h = (f16)v;
    hi[i] = h;
    lo[i] = (f16)(v - (float)h);
}

__global__ __launch_bounds__(256) void prep_bias(const float* __restrict__ bih,
                                                 const float* __restrict__ bhh,
                                                 const float* __restrict__ bfc,
                                                 const float* __restrict__ Wih,
                                                 float* __restrict__ b1,
                                                 float* __restrict__ bcmb) {
    int wave = blockIdx.x * 4 + (threadIdx.x >> 6);  // 64 waves total
    int lane = threadIdx.x & 63;
    for (int j = wave * 16; j < wave * 16 + 16; ++j) {
        float s = 0.f;
        for (int o = lane; o < 256; o += 64) s += bfc[o] * Wih[j * 256 + o];
        for (int off = 32; off; off >>= 1) s += __shfl_down(s, off);
        if (lane == 0) {
            float t = bih[j] + bhh[j];
            b1[j] = t;
            bcmb[j] = t + s;
        }
    }
}

__global__ __launch_bounds__(256) void prep_wcmb(const float* __restrict__ Wih,
                                                 const float* __restrict__ Wfc,
                                                 const float* __restrict__ Whh,
                                                 f16* __restrict__ Bt_hi,
                                                 f16* __restrict__ Bt_lo) {
    __shared__ float As[64][65];
    __shared__ float Bs[64][65];
    int j0 = blockIdx.y * 64, k0 = blockIdx.x * 64;
    int tid = threadIdx.x;
    float acc[4][4] = {};
    for (int o0 = 0; o0 < 256; o0 += 64) {
        __syncthreads();
        #pragma unroll
        for (int i = 0; i < 16; ++i) {
            int e = i * 256 + tid;
            int r = e >> 6, c = e & 63;
            As[r][c] = Wih[(j0 + r) * 256 + o0 + c];
            Bs[r][c] = Wfc[(o0 + r) * 1024 + k0 + c];
        }
        __syncthreads();
        int ty = tid >> 4, tx = tid & 15;
        for (int o = 0; o < 64; ++o) {
            float a[4], b[4];
            #pragma unroll
            for (int i = 0; i < 4; ++i) a[i] = As[ty * 4 + i][o];
            #pragma unroll
            for (int i = 0; i < 4; ++i) b[i] = Bs[o][tx * 4 + i];
            #pragma unroll
            for (int i = 0; i < 4; ++i)
                #pragma unroll
                for (int jj = 0; jj < 4; ++jj) acc[i][jj] += a[i] * b[jj];
        }
    }
    int ty = tid >> 4, tx = tid & 15;
    #pragma unroll
    for (int i = 0; i < 4; ++i)
        #pragma unroll
        for (int jj = 0; jj < 4; ++jj) {
            int j = j0 + ty * 4 + i, k = k0 + tx * 4 + jj;
            float v = acc[i][jj] + Whh[j * 1024 + k];
            f16 h = (f16)v;
            Bt_hi[j * 1024 + k] = h;
            Bt_lo[j * 1024 + k] = (f16)(v - (float)h);
        }
}

// DVFS pre-boost: ~130us of dense MFMA at full clock (longer at low clock,
// which is exactly when we need the boost). Runs before the rollout.
__global__ __launch_bounds__(256) void burner() {
    f16x8 o = {};
    #pragma unroll
    for (int j = 0; j < 8; ++j) o[j] = (f16)1.0f;
    f32x4 a0 = {}, a1 = {}, a2 = {}, a3 = {};
    for (int i = 0; i < 2048; ++i) {
        a0 = MFMA16(o, o, a0, 0, 0, 0);
        a1 = MFMA16(o, o, a1, 0, 0, 0);
        a2 = MFMA16(o, o, a2, 0, 0, 0);
        a3 = MFMA16(o, o, a3, 0, 0, 0);
        a0 = MFMA16(o, o, a0, 0, 0, 0);
        a1 = MFMA16(o, o, a1, 0, 0, 0);
        a2 = MFMA16(o, o, a2, 0, 0, 0);
        a3 = MFMA16(o, o, a3, 0, 0, 0);
    }
    asm volatile("" :: "v"(a0), "v"(a1), "v"(a2), "v"(a3));
}

// ---------------- rollout helpers ----------------

// Coherent (placement-safe) 16B load from the device coherence point.
__device__ __forceinline__ void ld_sc16(f16x8& d, const f16* p) {
    asm volatile("global_load_dwordx4 %0, %1, off sc0 sc1"
                 : "=&v"(d) : "v"(p) : "memory");
}

// Spin with MFMA burn: two interleaved dependent junk-MFMA chains keep the
// matrix pipe visibly busy while waiting (DVFS signal + poll backoff).
__device__ __forceinline__ void spin_ge(const unsigned* p, unsigned tgt,
                                        bool& gaveup, f16x8 bo,
                                        f32x4& j0, f32x4& j1) {
    if (gaveup) return;
    int it = 0;
    while (__hip_atomic_load(p, __ATOMIC_RELAXED, __HIP_MEMORY_SCOPE_AGENT) < tgt) {
        #pragma unroll
        for (int j = 0; j < 8; ++j) {
            j0 = MFMA16(bo, bo, j0, 0, 0, 0);
            j1 = MFMA16(bo, bo, j1, 0, 0, 0);
        }
        if (++it > (1 << 13)) { gaveup = true; break; }
    }
    asm volatile("" : "+v"(j0), "+v"(j1));
}

__device__ __forceinline__ void store_h4(f16* ph, f16* pl, size_t off, f32x4 v) {
    u64 whi = 0, wlo = 0;
    #pragma unroll
    for (int j = 0; j < 4; ++j) {
        float t = v[j];
        f16 th = (f16)t;
        f16 tl = (f16)(t - (float)th);
        whi |= (u64)__builtin_bit_cast(u16, th) << (16 * j);
        wlo |= (u64)__builtin_bit_cast(u16, tl) << (16 * j);
    }
    __hip_atomic_store((u64*)(ph + off), whi, __ATOMIC_RELAXED, __HIP_MEMORY_SCOPE_AGENT);
    __hip_atomic_store((u64*)(pl + off), wlo, __ATOMIC_RELAXED, __HIP_MEMORY_SCOPE_AGENT);
}

// ---------------- persistent rollout ----------------
// 16 row-groups x 16 rows. Per group: 8 h-WGs (128 cols each) + 2 y-WGs.
// Wave w of every WG owns k-slice [w*128, w*128+128) == the columns written
// by producer h-WG w of the same group -> per-wave flag polling.
// Flags padded to 128 B each.

#define FLAG(g, s) (syncarea + ((g) * 10 + (s)) * 32)

__global__ __launch_bounds__(512, 1) void rollout(
    const f16* __restrict__ x0_hi, const f16* __restrict__ x0_lo,
    const f16* __restrict__ Wih_hi, const f16* __restrict__ Wih_lo,
    const f16* __restrict__ Bt_hi, const f16* __restrict__ Bt_lo,
    const float* __restrict__ b1, const float* __restrict__ bcmb,
    const float* __restrict__ bfc,
    f16* hh0, f16* hl0, f16* hh1, f16* hl1, f16* hh2, f16* hl2,
    float* __restrict__ traj, unsigned* __restrict__ syncarea) {
    __shared__ f16 Ws[64 * 1024];    // 128 KB: W_hi for k<512 (128 cols), swizzled
    __shared__ float Red[16 * 128];  // 8 KB reduction buffer, swizzled

    const int wg = blockIdx.x;
    const int g = wg & 15;    // row group: rows g*16 .. g*16+15
    const int cg = wg >> 4;   // 0..9: 0-7 = h cols cg*128; 8-9 = y cols
    const int tid = threadIdx.x;
    const int lane = tid & 63;
    const int w = tid >> 6;    // wave 0..7 = k-slice owner
    const int l15 = lane & 15;
    const int kq = lane >> 4;  // 0..3
    const bool is_h = (cg < 8);
    const int colbase = is_h ? cg * 128 : 1024 + (cg - 8) * 128;
    const int fr = tid >> 5;         // epilogue row 0..15
    const int fc = (tid & 31) * 4;   // epilogue col base 0..124

    bool gaveup = false;
    f16x8 bo = {};  // zero burn operand: MFMA(0,0,junk) keeps pipe busy, no inf
    f32x4 jk0 = {}, jk1 = {};

    // ---- stage W_hi (k < 512) to LDS, XOR-swizzled ----
    {
        const char* gsrc = (const char*)Bt_hi;
        #pragma unroll
        for (int i = 0; i < 16; ++i) {
            int f = (tid + i * 512) * 16;  // byte 0..131072
            int col = f >> 10;             // 0..127
            int kb = f & 1023;             // byte within k<512 row
            f16x8 v = *(const f16x8*)(gsrc + (size_t)(colbase + col) * 2048 + kb);
            *(f16x8*)((char*)Ws + (f ^ ((col & 7) << 4))) = v;
        }
    }
    __syncthreads();

    f32x4 biasv;
    {
        const float* bp = is_h ? (bcmb + colbase + fc) : (bfc + colbase - 1024 + fc);
        biasv = *(const f32x4*)bp;
    }
    const size_t hoff0 = (size_t)(g * 16 + l15) * 1024 + w * 128 + kq * 8;
    const size_t hwoff = (size_t)(g * 16 + fr) * 1024 + colbase + fc;

    // ---- step 1: h_1 = tanh(x0 @ Wih^T + b1) -> buf1 (h-WGs only) ----
    if (is_h) {
        *(f32x4*)&Red[tid * 4] = (f32x4){0.f, 0.f, 0.f, 0.f};
        const int k1 = w * 32 + kq * 8;  // K=256 split 8 ways
        f16x8 xh = *(const f16x8*)(x0_hi + (size_t)(g * 16 + l15) * 256 + k1);
        f16x8 xl = *(const f16x8*)(x0_lo + (size_t)(g * 16 + l15) * 256 + k1);
        f32x4 acc[8] = {};
        #pragma unroll
        for (int nt = 0; nt < 8; ++nt) {
            f16x8 wh = *(const f16x8*)(Wih_hi + (size_t)(colbase + nt * 16 + l15) * 256 + k1);
            f16x8 wl = *(const f16x8*)(Wih_lo + (size_t)(colbase + nt * 16 + l15) * 256 + k1);
            acc[nt] = MFMA16(wh, xh, acc[nt], 0, 0, 0);
            acc[nt] = MFMA16(wh, xl, acc[nt], 0, 0, 0);
            acc[nt] = MFMA16(wl, xh, acc[nt], 0, 0, 0);
        }
        __syncthreads();
        #pragma unroll
        for (int nt = 0; nt < 8; ++nt)
            #pragma unroll
            for (int p = 0; p < 4; ++p) {
                int r = l15, c = nt * 16 + kq * 4 + p;
                atomicAdd(&Red[(r * 128 + c) ^ ((r & 7) << 2)], acc[nt][p]);
            }
        __syncthreads();
        f32x4 v = *(const f32x4*)&Red[(fr * 128 + fc) ^ ((fr & 7) << 2)];
        const float* bp = b1 + colbase + fc;
        f32x4 tv;
        #pragma unroll
        for (int j = 0; j < 4; ++j) tv[j] = tanhf(v[j] + bp[j]);
        store_h4(hh1, hl1, hwoff, tv);
    }
    __syncthreads();  // drain stores
    if (tid == 0 && is_h)
        __hip_atomic_store(FLAG(g, cg), 1u, __ATOMIC_RELAXED, __HIP_MEMORY_SCOPE_AGENT);

    // ---- main loop: step t computes h_t (h-WGs) and y_{t-1} (y-WGs) ----
    f16 *pAh = hh1, *pAl = hl1, *pBh = hh2, *pBl = hl2, *pCh = hh0, *pCl = hl0;
    for (int t = 2; t <= 512; ++t) {
        if (t == 512 && is_h) break;  // y-WGs run one extra step for y_511
        // per-wave: wait for MY producer's slice of h_{t-1}
        spin_ge(FLAG(g, w), (unsigned)(t - 1), gaveup, bo, jk0, jk1);
        // issue h-slice loads (coherence point)
        f16x8 hf0, hf1, hf2, hf3, lf0, lf1, lf2, lf3;
        ld_sc16(hf0, pAh + hoff0);       ld_sc16(lf0, pAl + hoff0);
        ld_sc16(hf1, pAh + hoff0 + 32);  ld_sc16(lf1, pAl + hoff0 + 32);
        ld_sc16(hf2, pAh + hoff0 + 64);  ld_sc16(lf2, pAl + hoff0 + 64);
        ld_sc16(hf3, pAh + hoff0 + 96);  ld_sc16(lf3, pAl + hoff0 + 96);
        const f16x8 hf[4] = {hf0, hf1, hf2, hf3};
        const f16x8 lf[4] = {lf0, lf1, lf2, lf3};
        *(f32x4*)&Red[tid * 4] = (f32x4){0.f, 0.f, 0.f, 0.f};
        f32x4 acc[8] = {};
        const int swz = (l15 & 7) << 4;
        #pragma unroll
        for (int nt = 0; nt < 8; ++nt) {
            f16x8 wh[4], wl[4];
            #pragma unroll
            for (int kk = 0; kk < 4; ++kk) {
                int k = w * 128 + kq * 8 + kk * 32;
                if (w < 4) {
                    int byte = ((nt * 16 + l15) * 1024 + k * 2) ^ swz;
                    wh[kk] = *(const f16x8*)((const char*)Ws + byte);
                } else {
                    wh[kk] = *(const f16x8*)(Bt_hi + (size_t)(colbase + nt * 16 + l15) * 1024 + k);
                }
                wl[kk] = *(const f16x8*)(Bt_lo + (size_t)(colbase + nt * 16 + l15) * 1024 + k);
            }
            if (nt == 0) {
                asm volatile("s_waitcnt vmcnt(0)" ::: "memory");
                __builtin_amdgcn_sched_barrier(0);
            }
            #pragma unroll
            for (int kk = 0; kk < 4; ++kk) {
                acc[nt] = MFMA16(wh[kk], hf[kk], acc[nt], 0, 0, 0);
                acc[nt] = MFMA16(wh[kk], lf[kk], acc[nt], 0, 0, 0);
                acc[nt] = MFMA16(wl[kk], hf[kk], acc[nt], 0, 0, 0);
            }
        }
        __syncthreads();
        #pragma unroll
        for (int nt = 0; nt < 8; ++nt)
            #pragma unroll
            for (int p = 0; p < 4; ++p) {
                int r = l15, c = nt * 16 + kq * 4 + p;
                atomicAdd(&Red[(r * 128 + c) ^ ((r & 7) << 2)], acc[nt][p]);
            }
        // 3-buffer safety: h producers make sure y-WGs are within 2 steps
        if (tid == 0 && is_h && t >= 4) {
            spin_ge(FLAG(g, 8), (unsigned)(t - 2), gaveup, bo, jk0, jk1);
            spin_ge(FLAG(g, 9), (unsigned)(t - 2), gaveup, bo, jk0, jk1);
        }
        __syncthreads();
        f32x4 v = *(const f32x4*)&Red[(fr * 128 + fc) ^ ((fr & 7) << 2)];
        v += biasv;
        if (is_h) {
            f32x4 tv;
            #pragma unroll
            for (int j = 0; j < 4; ++j) tv[j] = tanhf(v[j]);
            store_h4(pBh, pBl, hwoff, tv);
        } else {
            *(f32x4*)(traj + (size_t)(t - 1) * 65536 + (size_t)(g * 16 + fr) * 256 +
                      (colbase - 1024) + fc) = v;
        }
        __syncthreads();  // drain stores before publishing
        if (tid == 0)
            __hip_atomic_store(FLAG(g, cg), (unsigned)t, __ATOMIC_RELAXED,
                               __HIP_MEMORY_SCOPE_AGENT);
        // rotate: next read = just-written; next write = spare
        f16 *th_ = pAh, *tl_ = pAl;
        pAh = pBh; pAl = pBl;
        pBh = pCh; pBl = pCl;
        pCh = th_; pCl = tl_;
    }
}

// ---------------- launch ----------------

extern "C" void kernel_launch(void* const* d_in, const int* in_sizes, int n_in,
                              void* d_out, int out_size, void* d_ws, size_t ws_size,
                              hipStream_t stream) {
    const float* x0 = (const float*)d_in[0];
    const float* Wih = (const float*)d_in[1];
    const float* bih = (const float*)d_in[2];
    const float* Whh = (const float*)d_in[3];
    const float* bhh = (const float*)d_in[4];
    const float* Wfc = (const float*)d_in[5];
    const float* bfc = (const float*)d_in[6];
    float* traj = (float*)d_out;  // [512][256][256]

    char* w = (char*)d_ws;
    size_t off = 0;
    f16* Bt_hi = (f16*)(w + off); off += 1280u * 1024 * 2;
    f16* Bt_lo = (f16*)(w + off); off += 1280u * 1024 * 2;
    f16* Wih_hi = (f16*)(w + off); off += 1024u * 256 * 2;
    f16* Wih_lo = (f16*)(w + off); off += 1024u * 256 * 2;
    f16* x0_hi = (f16*)(w + off); off += 256u * 256 * 2;
    f16* x0_lo = (f16*)(w + off); off += 256u * 256 * 2;
    f16* hh0 = (f16*)(w + off); off += 256u * 1024 * 2;
    f16* hl0 = (f16*)(w + off); off += 256u * 1024 * 2;
    f16* hh1 = (f16*)(w + off); off += 256u * 1024 * 2;
    f16* hl1 = (f16*)(w + off); off += 256u * 1024 * 2;
    f16* hh2 = (f16*)(w + off); off += 256u * 1024 * 2;
    f16* hl2 = (f16*)(w + off); off += 256u * 1024 * 2;
    float* b1 = (float*)(w + off); off += 4096;
    float* bcmb = (float*)(w + off); off += 4096;
    unsigned* syncarea = (unsigned*)(w + off); off += 32768;  // padded flags

    prep_copy_x0<<<dim3(256), dim3(256), 0, stream>>>(x0, traj, x0_hi, x0_lo, syncarea);
    prep_cast2<<<dim3(1024), dim3(256), 0, stream>>>(Wih, Wih_hi, Wih_lo);
    prep_bias<<<dim3(16), dim3(256), 0, stream>>>(bih, bhh, bfc, Wih, b1, bcmb);
    prep_cast2<<<dim3(1024), dim3(256), 0, stream>>>(Wfc, Bt_hi + 1024 * 1024,
                                                     Bt_lo + 1024 * 1024);
    prep_wcmb<<<dim3(16, 16), dim3(256), 0, stream>>>(Wih, Wfc, Whh, Bt_hi, Bt_lo);

    // DVFS pre-boost: dense MFMA across all CUs before the latency-sensitive
    // rollout (decisive test of the down-clock hypothesis).
    burner<<<dim3(256), dim3(256), 0, stream>>>();

    // persistent rollout: 160 WGs x 512 threads, 1 WG/CU (136 KB LDS).
    // Per-wave producer-matched flag sync (128B-padded flags); junk-MFMA
    // burn in every wait (sustained DVFS signal); coherence-point h traffic
    // -> placement-independent.
    rollout<<<dim3(NWG), dim3(512), 0, stream>>>(
        x0_hi, x0_lo, Wih_hi, Wih_lo, Bt_hi, Bt_lo, b1, bcmb, bfc,
        hh0, hl0, hh1, hl1, hh2, hl2, traj, syncarea);
}